// Round 9
// baseline (95.469 us; speedup 1.0000x reference)
//
#include <hip/hip_runtime.h>
#include <hip/hip_bf16.h>

typedef __bf16 bf16_t;
typedef __bf16 bf16x8 __attribute__((ext_vector_type(8)));
typedef __bf16 bf16x4 __attribute__((ext_vector_type(4)));
typedef short short4v __attribute__((ext_vector_type(4)));
typedef float f32x4 __attribute__((ext_vector_type(4)));

static_assert(sizeof(bf16x8) == 16, "bf16x8 must be 16B");

// Problem constants
#define BB 2
#define SS 2048
#define DD 512
#define HH 8
#define DH 64
#define LOG2E 1.44269504088896f
// HID == 512; head block = contiguous [2048,64] at (b*8+h)*131072

// ------------- prep: z=0..2 cast q/k/v f32->bf16; z=3 transpose+cast weights -------------
__global__ void prep(const float* __restrict__ q, const float* __restrict__ k,
                     const float* __restrict__ v, const float* __restrict__ w0,
                     const float* __restrict__ w1, const float* __restrict__ w2,
                     const float* __restrict__ w3, bf16_t* __restrict__ qkvb,
                     bf16_t* __restrict__ wt, int n) {
  const int tid = threadIdx.x;
  if (blockIdx.z < 3) {
    const float* src = (blockIdx.z == 0) ? q : (blockIdx.z == 1) ? k : v;
    bf16_t* out = qkvb + (size_t)blockIdx.z * n;
    int i = (blockIdx.x * 256 + tid) * 8;
    if (i >= n) return;
    const float4* s4 = (const float4*)(src + i);
    float4 a = s4[0], b = s4[1];
    bf16x8 o;
    o[0] = (bf16_t)a.x; o[1] = (bf16_t)a.y; o[2] = (bf16_t)a.z; o[3] = (bf16_t)a.w;
    o[4] = (bf16_t)b.x; o[5] = (bf16_t)b.y; o[6] = (bf16_t)b.z; o[7] = (bf16_t)b.w;
    *(bf16x8*)(out + i) = o;
  } else {
    // transpose+cast: Wt[nn][kk] = (bf16)W[kk][nn]
    __shared__ float tile[32][33];
    const int x = blockIdx.x;                  // 0..1023
    const int wsel = x >> 8;
    const int nb = ((x >> 4) & 15) * 32, kb = (x & 15) * 32;
    const int tx = tid & 31, ty = tid >> 5;    // (32,8)
    const float* W = (wsel == 0) ? w0 : (wsel == 1) ? w1 : (wsel == 2) ? w2 : w3;
    bf16_t* out = wt + (size_t)wsel * 512 * 512;
#pragma unroll
    for (int i = 0; i < 4; i++)
      tile[ty + i * 8][tx] = W[(size_t)(kb + ty + i * 8) * 512 + nb + tx];
    __syncthreads();
#pragma unroll
    for (int i = 0; i < 4; i++)
      out[(size_t)(nb + ty + i * 8) * 512 + kb + tx] = (bf16_t)tile[tx][ty + i * 8];
  }
}

// ------------- GEMM: C[M,N] = (A[M,K] @ Bt[N,K]^T + bias[N]) * (z==0 ? s0 : 1) ----------
// Templated tile: BM x BN, BK=64, 256 thr, 4 waves 2x2. global_load_lds(16B), dbuf LDS.
template <int BM, int BN, int WM, int WN, typename OutT>
__global__ __launch_bounds__(256) void gemm2(
    const bf16_t* __restrict__ Abase, const bf16_t* __restrict__ Btbase,
    const float* __restrict__ bias0, const float* __restrict__ bias1,
    const float* __restrict__ bias2, OutT* __restrict__ Cbase,
    int M, int N, int K, long Az, long Bz, long Cz, float scale0) {
  static_assert(BM == 2 * WM && BN == 2 * WN, "2x2 wave grid");
  constexpr int FM = WM / 16, FN = WN / 16;
  constexpr int AJ = BM / 32, BJ = BN / 32;

  const bf16_t* A  = Abase + (size_t)blockIdx.z * Az;
  const bf16_t* Bt = Btbase + (size_t)blockIdx.z * Bz;
  const float* bias = (blockIdx.z == 0) ? bias0 : (blockIdx.z == 1) ? bias1 : bias2;
  OutT* C = Cbase + (size_t)blockIdx.z * Cz;
  const float osc = (blockIdx.z == 0) ? scale0 : 1.0f;

  __shared__ bf16_t As[2][BM * 64];
  __shared__ bf16_t Bs[2][BN * 64];

  const int tid = threadIdx.x, w = tid >> 6, l = tid & 63;
  const int bm = blockIdx.y, bn = blockIdx.x;
  const int wm0 = (w >> 1) * WM, wn0 = (w & 1) * WN;
  const int lr = l & 15, lg = l >> 4;

  f32x4 acc[FM][FN] = {};

  auto stage = [&](int buf, int kt) {
#pragma unroll
    for (int j = 0; j < AJ; j++) {
      int lin = j * 256 + tid;              // 16B-chunk index
      int row = lin >> 3, cc = lin & 7;
      const bf16_t* g = A + (size_t)(bm * BM + row) * K + kt * 64 + cc * 8;
      __builtin_amdgcn_global_load_lds(
          (const __attribute__((address_space(1))) void*)g,
          (__attribute__((address_space(3))) void*)(&As[buf][(j * 256 + w * 64) * 8]), 16, 0, 0);
    }
#pragma unroll
    for (int j = 0; j < BJ; j++) {
      int lin = j * 256 + tid;
      int row = lin >> 3, cc = lin & 7;
      const bf16_t* g = Bt + (size_t)(bn * BN + row) * K + kt * 64 + cc * 8;
      __builtin_amdgcn_global_load_lds(
          (const __attribute__((address_space(1))) void*)g,
          (__attribute__((address_space(3))) void*)(&Bs[buf][(j * 256 + w * 64) * 8]), 16, 0, 0);
    }
  };

  stage(0, 0);
  const int KT = K >> 6;
  for (int kt = 0; kt < KT; kt++) {
    __syncthreads();                         // drains vmcnt -> buf[kt&1] ready
    if (kt + 1 < KT) stage((kt + 1) & 1, kt + 1);
    const bf16_t* as = As[kt & 1];
    const bf16_t* bs = Bs[kt & 1];
#pragma unroll
    for (int kc = 0; kc < 2; kc++) {
      bf16x8 a[FM], b[FN];
#pragma unroll
      for (int i = 0; i < FM; i++)
        a[i] = *(const bf16x8*)(as + (wm0 + i * 16 + lr) * 64 + kc * 32 + lg * 8);
#pragma unroll
      for (int j = 0; j < FN; j++)
        b[j] = *(const bf16x8*)(bs + (wn0 + j * 16 + lr) * 64 + kc * 32 + lg * 8);
#pragma unroll
      for (int i = 0; i < FM; i++)
#pragma unroll
        for (int j = 0; j < FN; j++)
          acc[i][j] = __builtin_amdgcn_mfma_f32_16x16x32_bf16(a[i], b[j], acc[i][j], 0, 0, 0);
    }
  }

  // epilogue: C row = (lane>>4)*4+reg, col = lane&15 (verified m89/m91 layout)
  const int row0 = bm * BM + wm0, col0 = bn * BN + wn0;
#pragma unroll
  for (int j = 0; j < FN; j++) {
    int col = col0 + j * 16 + lr;
    float bv = bias[col];
#pragma unroll
    for (int i = 0; i < FM; i++) {
      int row = row0 + i * 16 + lg * 4;
#pragma unroll
      for (int r = 0; r < 4; r++) {
        float vv = (acc[i][j][r] + bv) * osc;
        C[(size_t)(row + r) * N + col] = (OutT)vv;
      }
    }
  }
}

// ------------- flash attention, KV-split x2, 1-deep software pipeline -------------
// grid 1024: id -> bh low3 (XCD-affinity), bh hi, qt, half. 4 waves, QBLK=64.
// Pipeline: at body T, issue QK(T) MFMAs right after the barrier, then run
// softmax+PV of tile T-1 on the VALU while QK(T) executes (separate pipes).
// K LDS 2-deep (16KB), V LDS 3-deep (24KB) -> 40KB = exactly 4 blocks/CU.
// Softmax in exp2 domain (Q pre-scaled by log2e in the GEMM epilogue);
// per-lane deferred l reduction. All layouts verbatim from the R7 passed kernel.
__global__ __launch_bounds__(256) void attn_flash(const bf16_t* __restrict__ qp,
                                                  const bf16_t* __restrict__ kp,
                                                  const bf16_t* __restrict__ vp,
                                                  float* __restrict__ Opart,
                                                  float* __restrict__ mlpart) {
  const int id = blockIdx.x;
  const int bh = (id & 7) | (((id >> 3) & 1) << 3);
  const int qt = (id >> 4) & 31;
  const int half = id >> 9;
  const int pidx = (((qt << 4) | bh) << 1) + half;

  const int tid = threadIdx.x, w = tid >> 6, l = tid & 63;
  const int lr = l & 15, lg = l >> 4;
  const size_t hb = (size_t)bh * (SS * DH);
  const bf16_t* Q = qp + hb;
  const bf16_t* Kh = kp + hb;
  const bf16_t* Vh = vp + hb;

  __shared__ __align__(16) bf16_t KsL[2][4096];    // 16KB, K tiles (swizzled rows)
  __shared__ __align__(16) bf16_t VtL[3][4096];    // 24KB, V^T tiles (swizzled rows)

  const int qr0 = qt * 64 + w * 16;

  bf16x8 aq[2];
#pragma unroll
  for (int kc = 0; kc < 2; kc++)
    aq[kc] = *(const bf16x8*)(Q + (size_t)(qr0 + lr) * DH + kc * 32 + lg * 8);

  f32x4 o[4] = {};                    // O^T[d = n*16+lg*4+r][q = lr]
  float m_run = -1e30f, l_run = 0.f;  // log2-domain m; per-lane partial l

  // K staging source (pre-swizzled, R7-verbatim)
  const int krow = (w << 3) + (l >> 3);
  const int kcol = ((l & 7) ^ (l >> 3)) << 3;
  const bf16_t* ks_it = Kh + (size_t)(half * 16) * 4096 + krow * 64 + kcol;

  auto stage_k = [&](int buf, const bf16_t* ks) {
    char* kb = (char*)&KsL[buf][0];
    __builtin_amdgcn_global_load_lds((const __attribute__((address_space(1))) void*)ks,
        (__attribute__((address_space(3))) void*)(kb + (w << 10)), 16, 0, 0);
    __builtin_amdgcn_global_load_lds((const __attribute__((address_space(1))) void*)(ks + 2048),
        (__attribute__((address_space(3))) void*)(kb + 4096 + (w << 10)), 16, 0, 0);
  };

  // V staging (reg roundtrip, R7-verbatim; buf now 0..2)
  const int vk0 = l, vd0 = w;
  const int vd1 = 4 + w;
  bf16x8 vreg0, vreg1;
  auto load_v = [&](int it) {
    const size_t kv0 = (size_t)it * 64;
    vreg0 = *(const bf16x8*)(Vh + (kv0 + vk0) * DH + vd0 * 8);
    vreg1 = *(const bf16x8*)(Vh + (kv0 + vk0) * DH + vd1 * 8);
  };
  auto write_v = [&](int buf) {
    char* vt = (char*)&VtL[buf][0];
#pragma unroll
    for (int j = 0; j < 8; j++) {
      int d0 = vd0 * 8 + j;
      *(bf16_t*)(vt + d0 * 128 + ((vk0 * 2) ^ (j << 4))) = vreg0[j];
    }
#pragma unroll
    for (int j = 0; j < 8; j++) {
      int d1 = vd1 * 8 + j;
      *(bf16_t*)(vt + d1 * 128 + ((vk0 * 2) ^ (j << 4))) = vreg1[j];
    }
  };

  const int it0 = half * 16;
  stage_k(0, ks_it);
  load_v(it0);
  write_v(0);

  f32x4 sA[4], sB[4];

#pragma unroll
  for (int T = 0; T <= 16; T++) {
    __syncthreads();                 // publishes K(T) gload + V(T) writes

    // --- QK(T): issue early; MFMA executes while we do SM/PV(T-1) below ---
    if (T < 16) {
      f32x4* sc = (T & 1) ? sB : sA;
      const char* ksb = (const char*)&KsL[T & 1][0];
#pragma unroll
      for (int n = 0; n < 4; n++) sc[n] = f32x4{0.f, 0.f, 0.f, 0.f};
      __builtin_amdgcn_s_setprio(1);
#pragma unroll
      for (int kc = 0; kc < 2; kc++) {
#pragma unroll
        for (int n = 0; n < 4; n++) {
          bf16x8 bk = *(const bf16x8*)(ksb + (n * 16 + lr) * 128 +
                                       ((kc * 64 + lg * 16) ^ ((lr & 7) << 4)));
          sc[n] = __builtin_amdgcn_mfma_f32_16x16x32_bf16(bk, aq[kc], sc[n], 0, 0, 0);
        }
      }
      __builtin_amdgcn_s_setprio(0);
    }

    // --- issue next tile's staging (consumed at end of body; latency hidden) ---
    if (T + 1 < 16) {
      ks_it += 4096;
      stage_k((T + 1) & 1, ks_it);
      load_v(it0 + T + 1);
    }

    // --- SM + PV of tile T-1 (VALU/DS while QK(T) MFMAs drain) ---
    if (T >= 1) {
      f32x4* sp = (T & 1) ? sA : sB;

      float pmax = -1e30f;
#pragma unroll
      for (int n = 0; n < 4; n++)
#pragma unroll
        for (int r = 0; r < 4; r++) pmax = fmaxf(pmax, sp[n][r]);
      pmax = fmaxf(pmax, __shfl_xor(pmax, 16));
      pmax = fmaxf(pmax, __shfl_xor(pmax, 32));
      if (!__all(pmax <= m_run + 8.0f)) {
        float mnew = fmaxf(m_run, pmax);
        float scale = exp2f(m_run - mnew);   // row-uniform per lane
        l_run *= scale;
#pragma unroll
        for (int n = 0; n < 4; n++)
#pragma unroll
          for (int r = 0; r < 4; r++) o[n][r] *= scale;
        m_run = mnew;
      }
      float rs = 0.f;
#pragma unroll
      for (int n = 0; n < 4; n++)
#pragma unroll
        for (int r = 0; r < 4; r++) {
          float e = exp2f(sp[n][r] - m_run);
          sp[n][r] = e;
          rs += e;
        }
      l_run += rs;                          // cross-lane sum deferred to end

      short4v pb[4];
#pragma unroll
      for (int c2 = 0; c2 < 4; c2++) {
        bf16x4 t;
#pragma unroll
        for (int r = 0; r < 4; r++) t[r] = (bf16_t)sp[c2][r];
        pb[c2] = __builtin_bit_cast(short4v, t);
      }
      const char* vtb = (const char*)&VtL[(T - 1) % 3][0];
      __builtin_amdgcn_s_setprio(1);
#pragma unroll
      for (int n = 0; n < 4; n++) {
#pragma unroll
        for (int c2 = 0; c2 < 4; c2++) {
          bf16x4 bvh = *(const bf16x4*)(vtb + (n * 16 + lr) * 128 +
                                        ((c2 * 32 + lg * 8) ^ ((lr & 7) << 4)));
          o[n] = __builtin_amdgcn_mfma_f32_16x16x16bf16_1k(
              __builtin_bit_cast(short4v, bvh), pb[c2], o[n], 0, 0, 0);
        }
      }
      __builtin_amdgcn_s_setprio(0);
    }

    // --- consume in-flight V loads into buffer (T+1)%3 (freed: PV(T-2) done) ---
    if (T + 1 < 16) write_v((T + 1) % 3);
  }

  // final cross-lane l reduction (deferred)
  l_run += __shfl_xor(l_run, 16);
  l_run += __shfl_xor(l_run, 32);

  // --- write partials: O^T lane-order (coalesced), m (log2-domain) / l per q-row ---
  float* ob = Opart + (size_t)pidx * 4096;
#pragma unroll
  for (int n = 0; n < 4; n++)
    *(f32x4*)(ob + ((w * 4 + n) * 64 + l) * 4) = o[n];
  if (lg == 0) {
    mlpart[(size_t)pidx * 128 + (w * 16 + lr) * 2 + 0] = m_run;
    mlpart[(size_t)pidx * 128 + (w * 16 + lr) * 2 + 1] = l_run;
  }
}

// ------------- combine the two KV-halves -> ctx (bf16); m's are log2-domain -------------
__global__ __launch_bounds__(256) void attn_combine(const float* __restrict__ Opart,
                                                    const float* __restrict__ mlpart,
                                                    bf16_t* __restrict__ ctx) {
  const int id = blockIdx.x;                 // 512 = qt*16 + bh
  const int qt = id >> 4, bh = id & 15;
  const int t = threadIdx.x, w = t >> 6, l = t & 63;
  const int lr = l & 15, lg = l >> 4;
  const int p0 = id * 2, p1 = id * 2 + 1;
  const int q = w * 16 + lr;

  float m1 = mlpart[(size_t)p0 * 128 + q * 2 + 0];
  float l1 = mlpart[(size_t)p0 * 128 + q * 2 + 1];
  float m2 = mlpart[(size_t)p1 * 128 + q * 2 + 0];
  float l2 = mlpart[(size_t)p1 * 128 + q * 2 + 1];
  float m = fmaxf(m1, m2);
  float e1 = exp2f(m1 - m), e2 = exp2f(m2 - m);
  float denom = (l1 * e1 + l2 * e2) * 8.0f;     // /sqrt(DH) after softmax
  float f1 = e1 / denom, f2 = e2 / denom;

  const int b = bh >> 3, h = bh & 7;
  const int trow = qt * 64 + q;
  size_t rowbase = ((size_t)b * SS + trow) * 512 + h * 64;

  const float* oa = Opart + (size_t)p0 * 4096;
  const float* obp = Opart + (size_t)p1 * 4096;
#pragma unroll
  for (int n = 0; n < 4; n++) {
    f32x4 a = *(const f32x4*)(oa + ((w * 4 + n) * 64 + l) * 4);
    f32x4 b2 = *(const f32x4*)(obp + ((w * 4 + n) * 64 + l) * 4);
    bf16x4 ov;
#pragma unroll
    for (int r = 0; r < 4; r++) ov[r] = (bf16_t)(a[r] * f1 + b2[r] * f2);
    *(bf16x4*)(&ctx[rowbase + n * 16 + lg * 4]) = ov;
  }
}

// ---------------- launcher ----------------
extern "C" void kernel_launch(void* const* d_in, const int* in_sizes, int n_in,
                              void* d_out, int out_size, void* d_ws, size_t ws_size,
                              hipStream_t stream) {
  const float* q  = (const float*)d_in[0];
  const float* k  = (const float*)d_in[1];
  const float* v  = (const float*)d_in[2];
  const float* Wq = (const float*)d_in[3];
  const float* bq = (const float*)d_in[4];
  const float* Wk = (const float*)d_in[5];
  const float* bk = (const float*)d_in[6];
  const float* Wv = (const float*)d_in[7];
  const float* bv = (const float*)d_in[8];
  const float* Wo = (const float*)d_in[9];
  const float* bo = (const float*)d_in[10];

  const size_t NQKV = (size_t)4096 * 512;   // 2,097,152 elems per tensor
  const size_t NW = (size_t)512 * 512;

  bf16_t* ws   = (bf16_t*)d_ws;
  bf16_t* wt   = ws;                 // 2 MB
  bf16_t* proj = wt + 4 * NW;        // 12 MB
  bf16_t* ctx  = proj + 3 * NQKV;    // 4 MB
  bf16_t* qkvb = ctx + NQKV;         // 12 MB (dead after QKV GEMM)
  float* Opart  = (float*)qkvb;      // 16 MB  (1024 partials x 4096 f32)
  float* mlpart = Opart + (size_t)1024 * 4096;  // 0.5 MB

  // 1. cast q,k,v -> bf16 (z=0..2) + transpose+cast weights (z=3)
  prep<<<dim3(1024, 1, 4), 256, 0, stream>>>(q, k, v, Wq, Wk, Wv, Wo, qkvb, wt, (int)NQKV);
  // 2. fused QKV projections; Q output pre-scaled by log2e (exp2-domain softmax)
  gemm2<128, 64, 64, 32, bf16_t><<<dim3(8, 32, 3), 256, 0, stream>>>(
      qkvb, wt, bq, bk, bv, proj, 4096, 512, 512, (long)NQKV, (long)NW, (long)NQKV, LOG2E);
  // 3. flash attention, KV-split x2 (1024 blocks, XCD-affine), pipelined
  attn_flash<<<1024, 256, 0, stream>>>(proj, proj + NQKV, proj + 2 * NQKV, Opart, mlpart);
  // 4. combine halves -> ctx
  attn_combine<<<512, 256, 0, stream>>>(Opart, mlpart, ctx);
  // 5. output projection (f32 out)
  gemm2<64, 64, 32, 32, float><<<dim3(8, 64, 1), 256, 0, stream>>>(
      ctx, wt + 3 * NW, bo, bo, bo, (float*)d_out, 4096, 512, 512, 0, 0, 0, 1.0f);
}